// Round 11
// baseline (291.015 us; speedup 1.0000x reference)
//
#include <hip/hip_runtime.h>

// Problem constants (match reference)
#define C 80
#define P 30000
#define G 800
#define BS 256
#define NB 16           // 64-px cells over [0,1024); boxes binned by CENTER
#define NC (NB * NB)    // 256 cells per class
#define PPTM 8          // sorted slots per thread in match
#define TPBM (BS * PPTM)// 2048 sorted slots per match block
#define MPART ((P + TPBM - 1) / TPBM)   // 15 parts per class
#define HCH 8           // hist chunks per class (finale parallelism)
#define CHSZ ((P + HCH - 1) / HCH)   // 3750

// Center-binning prune (validated absmax 0.0 across rounds 1-5,7-10): IoU>0.5
// forces each box to contain the other's center in both dims, so any viable
// GT's center lies strictly inside the pred box -> candidate cells are
// exactly the cells the pred box overlaps. Pruned pairs provably have
// IoU <= 0.5; validity re-verified with the bit-exact reference division.
//
// Round-11: round-10's match is LATENCY-bound, not issue- or BW-bound:
// unroll-1 made each rep a serial pIdx->addr->4-load->compute chain (8 deep
// per thread, ~900cy HBM each, ~2.5 waves/SIMD); and grid (15,80) spread a
// class's 15 blocks over all 8 XCDs, replicating the 840KB class slab in
// every XCD's L2 (FETCH 172MB = 2.6x pred). Fix A: 3-phase ILP batching
// (all pIdx loads -> all box loads -> compute) = 2 round trips, 32
// outstanding loads. Fix B: XCD swizzle id=(c%8)+8*(part+15*(c/8)) keeps a
// class's blocks on one XCD (heuristic only — correctness unaffected).
// Round-9 control run (pred in LDS, no gather) proved coherence alone gives
// ~101us and gather latency is the remaining term.
//
// Round-7 lesson kept everywhere: atomically-accumulated buffers (predCnt,
// gHist) cross a KERNEL BOUNDARY before being plain-read (XCD coherence).

// rank order = score desc, then pred-index asc. Packed key is monotone in
// that order (scores >= 0 so float bits are order-preserving). key==0 means
// "no match" (needs score==0.0f AND p==P-1 — probability ~0).
__device__ __forceinline__ unsigned long long pack_key(float s, int p) {
    return ((unsigned long long)__float_as_uint(s) << 32) | (unsigned)(P - 1 - p);
}

__device__ __forceinline__ int cell_coord(float v) {
    return min(max((int)(v * (1.0f / 64.0f)), 0), NB - 1);
}

__device__ __forceinline__ int cell_of_center(float cxf, float cyf) {
    return cell_coord(cyf) * NB + cell_coord(cxf);
}

// ---------------- gt binning: one block per class (count+scan+scatter) ------
// (verbatim round 10 — passed.) BS == NC == 256: thread t owns cell t.
// Zeroes this class's gtKey, gHist, predCnt, predCur, ticket.
__global__ __launch_bounds__(BS) void gt_bin_kernel(
        const float* __restrict__ gt,
        unsigned short* __restrict__ gtCnt, unsigned short* __restrict__ gtOff,
        float4* __restrict__ gtBox, float* __restrict__ gtAbe,
        unsigned short* __restrict__ gtIdx,
        unsigned long long* __restrict__ gtKey, int* __restrict__ gHist,
        int* __restrict__ predCnt, int* __restrict__ predCur,
        unsigned int* __restrict__ doneCnt) {
    __shared__ int h[NC], cur[NC];
    __shared__ int gcell[G];
    const int c = blockIdx.x, tid = threadIdx.x;
    h[tid] = 0;
    predCnt[c * NC + tid] = 0;                                       // folded init
    predCur[c * NC + tid] = 0;                                       // folded init
    if (c == 0 && tid == 0) *doneCnt = 0u;                           // folded init
    for (int i = tid; i < G; i += BS) gtKey[c * G + i] = 0ull;       // folded init
    for (int j = tid; j < 1024; j += BS) gHist[c * 1024 + j] = 0;    // folded init
    __syncthreads();
    for (int i = tid; i < G; i += BS) {
        const float* r = gt + ((size_t)c * G + i) * 7;
        int cl = cell_of_center(0.5f * (r[3] + r[5]), 0.5f * (r[4] + r[6]));
        gcell[i] = cl;
        atomicAdd(&h[cl], 1);
    }
    __syncthreads();
    const int v = h[tid];
    cur[tid] = v;
    __syncthreads();
    for (int o = 1; o < NC; o <<= 1) {   // inclusive scan, 8 steps
        int t = (tid >= o) ? cur[tid - o] : 0;
        __syncthreads();
        cur[tid] += t;
        __syncthreads();
    }
    const int excl = cur[tid] - v;
    gtOff[c * NC + tid] = (unsigned short)excl;
    gtCnt[c * NC + tid] = (unsigned short)v;
    __syncthreads();
    cur[tid] = excl;
    __syncthreads();
    for (int i = tid; i < G; i += BS) {
        const float* r = gt + ((size_t)c * G + i) * 7;   // L1-hot (2nd pass)
        float x1 = r[3], y1 = r[4], x2 = r[5], y2 = r[6];
        int slot = atomicAdd(&cur[gcell[i]], 1);
        gtBox[c * G + slot] = make_float4(x1, y1, x2, y2);
        // area + eps pre-folded: cross-compare uses sb = A + (area_g + eps);
        // the -inter terms of the two denominators cancel algebraically.
        gtAbe[c * G + slot] = __fadd_rn(__fmul_rn(__fsub_rn(x2, x1), __fsub_rn(y2, y1)), 1e-9f);
        gtIdx[c * G + slot] = (unsigned short)i;
    }
}

// ---------------- pprep: per-(class,cell) counts + cell cache ----------
// (verbatim round 10 — passed.)
__global__ __launch_bounds__(BS) void pprep_kernel(
        const float* __restrict__ pred, int* __restrict__ predCnt,
        unsigned char* __restrict__ cellB) {
    __shared__ int h[NC];
    const int c = blockIdx.y, tid = threadIdx.x;
    h[tid] = 0;
    __syncthreads();
    int p = blockIdx.x * BS + tid;
    if (p < P) {
        const float* r = pred + ((size_t)c * P + p) * 7;
        int cl = cell_of_center(0.5f * (r[3] + r[5]), 0.5f * (r[4] + r[6]));
        cellB[(size_t)c * P + p] = (unsigned char)cl;   // NC==256 fits uchar
        atomicAdd(&h[cl], 1);
    }
    __syncthreads();
    if (h[tid]) atomicAdd(&predCnt[c * NC + tid], h[tid]);   // no-return
}

// ---------------- pscatter: cell-sorted ushort index scatter ----------
// (verbatim round 10 — passed.)
__global__ __launch_bounds__(BS) void pscatter_kernel(
        const unsigned char* __restrict__ cellB, const int* __restrict__ predCnt,
        int* __restrict__ predCur, unsigned short* __restrict__ pIdxS) {
    __shared__ int h[NC], base[NC], sc[NC];
    const int c = blockIdx.y, tid = threadIdx.x;
    h[tid] = 0;
    sc[tid] = predCnt[c * NC + tid];
    const int v = sc[tid];
    __syncthreads();
    int p = blockIdx.x * BS + tid;
    int cellv = 0, lr = 0;
    if (p < P) {
        cellv = cellB[(size_t)c * P + p];
        lr = atomicAdd(&h[cellv], 1);   // LDS, local rank
    }
    __syncthreads();
    for (int o = 1; o < NC; o <<= 1) {  // inclusive scan (proven pattern)
        int t = (tid >= o) ? sc[tid - o] : 0;
        __syncthreads();
        sc[tid] += t;
        __syncthreads();
    }
    if (h[tid]) base[tid] = (sc[tid] - v) + atomicAdd(&predCur[c * NC + tid], h[tid]);
    __syncthreads();
    if (p < P) pIdxS[(size_t)c * P + base[cellv] + lr] = (unsigned short)p;
}

// ---------------- match: wave-coherent slots + ILP batch + XCD swizzle ----
// 1D grid of 1200: id = (c%8) + 8*(part + 15*(c/8)) -> all 15 parts of a
// class share id%8 (one XCD under the %NXCD dispatch heuristic): the class
// slab is fetched into ONE L2 instead of 8. 3-phase per-thread structure:
// (1) all PPTM pIdx loads, (2) all PPTM*4 box-coord loads, (3) compute —
// 2 memory round trips instead of 9-deep serial chains. Pair arithmetic,
// GT order, epilogue bit-identical to proven rounds 2-10.
__global__ __launch_bounds__(BS) void match11_kernel(
        const float* __restrict__ pred, const unsigned short* __restrict__ pIdxS,
        const unsigned short* __restrict__ gtOff, const unsigned short* __restrict__ gtCnt,
        const float4* __restrict__ gtBox, const float* __restrict__ gtAbe,
        const unsigned short* __restrict__ gtIdx,
        unsigned long long* __restrict__ gtKey) {
    __shared__ float4 sB[G];                        // 12.8 KB
    __shared__ float  sE[G];                        //  3.2 KB
    __shared__ unsigned short sG[G];                //  1.6 KB
    __shared__ unsigned short sOff[NC], sCnt[NC];   //  1.0 KB => 18.6 KB
    const int id  = blockIdx.x;
    const int xcd = id & 7;
    const int q   = id >> 3;
    const int part = q % MPART;
    const int c    = xcd + 8 * (q / MPART);
    const int tid = threadIdx.x;
    const int s0 = part * TPBM;

    for (int i = tid; i < G; i += BS) {
        sB[i] = gtBox[c * G + i];
        sE[i] = gtAbe[c * G + i];
        sG[i] = gtIdx[c * G + i];
    }
    sOff[tid] = gtOff[c * NC + tid];   // BS == NC
    sCnt[tid] = gtCnt[c * NC + tid];
    __syncthreads();

    const size_t cp = (size_t)c * P;

    // ---- phase 1: batch all pIdx loads (coalesced) ----
    int pA[PPTM];
    #pragma unroll
    for (int rep = 0; rep < PPTM; ++rep) {
        const int slot = s0 + rep * BS + tid;
        pA[rep] = (slot < P) ? (int)pIdxS[cp + slot] : -1;
    }
    // ---- phase 2: batch all box loads (32 outstanding, L2-hot slab) ----
    float bx[PPTM][4];
    #pragma unroll
    for (int rep = 0; rep < PPTM; ++rep) {
        if (pA[rep] >= 0) {
            const float* r = pred + (cp + pA[rep]) * 7;
            bx[rep][0] = r[3]; bx[rep][1] = r[4];
            bx[rep][2] = r[5]; bx[rep][3] = r[6];
        }
    }
    // ---- phase 3: compute ----
    #pragma unroll 1
    for (int rep = 0; rep < PPTM; ++rep) {
        if (pA[rep] >= 0) {
            const int p = pA[rep];
            float ax1 = bx[rep][0], ay1 = bx[rep][1];
            float ax2 = bx[rep][2], ay2 = bx[rep][3];
            float A = __fmul_rn(__fsub_rn(ax2, ax1), __fsub_rn(ay2, ay1));
            // candidate cells: those the pred box overlaps (any GT center
            // with iou>0.5 lies strictly inside the pred box)
            const int x0 = cell_coord(ax1), x1 = cell_coord(ax2);
            const int y0 = cell_coord(ay1), y1 = cell_coord(ay2);
            float IN = 0.0f, SB = 1.0f;
            int mj = -1;
            for (int yy = y0; yy <= y1; ++yy) {
                const int rowb = yy * NB;
                const int jb = sOff[rowb + x0];
                const int je = sOff[rowb + x1] + sCnt[rowb + x1];
                #pragma unroll 2
                for (int j = jb; j < je; ++j) {
                    float4 b = sB[j];
                    float lx = fmaxf(ax1, b.x), ly = fmaxf(ay1, b.y);
                    float rx = fminf(ax2, b.z), ry = fminf(ay2, b.w);
                    float wx = fmaxf(__fsub_rn(rx, lx), 0.0f);
                    float wy = fmaxf(__fsub_rn(ry, ly), 0.0f);
                    float in = __fmul_rn(wx, wy);
                    float sb = __fadd_rn(A, sE[j]);
                    bool  up = __fmul_rn(in, SB) > __fmul_rn(IN, sb);
                    IN = up ? in : IN; SB = up ? sb : SB; mj = up ? j : mj;
                }
            }
            if (IN > 0.0f) {   // zero-inter preds can never be valid
                float4 b = sB[mj];
                float area = __fmul_rn(__fsub_rn(b.z, b.x), __fsub_rn(b.w, b.y));
                float dn = __fadd_rn(__fsub_rn(__fadd_rn(A, area), IN), 1e-9f);
                float iou = __fdiv_rn(IN, dn);   // exact reference value
                if (iou > 0.5f) {
                    float sscore = pred[(cp + p) * 7 + 2];   // rare path, L1-hot line
                    atomicMax(&gtKey[c * G + sG[mj]], pack_key(sscore, p));
                }
            }
        }
    }
}

// ---------------- histf: compact+sort (x8 redundant) + chunked hist ------
// (verbatim round 10 — passed.) gHist consumed only in the NEXT launch.
__global__ __launch_bounds__(BS) void histf_kernel(
        const float* __restrict__ pred,
        const unsigned long long* __restrict__ gtKey,
        int* __restrict__ gHist, int* __restrict__ sortT) {
    __shared__ unsigned long long k[G];     // 6.4 KB compacted keys
    __shared__ unsigned long long sk[1024]; // 8 KB sorted-desc keys (pad=0)
    __shared__ int h[1024];                 // 4 KB local hist
    __shared__ int cnt;
    const int c = blockIdx.y, chunk = blockIdx.x, tid = threadIdx.x;

    if (tid == 0) cnt = 0;
    for (int j = tid; j < 1024; j += BS) { sk[j] = 0ull; h[j] = 0; }
    __syncthreads();
    for (int i = tid; i < G; i += BS) {
        unsigned long long key = gtKey[c * G + i];
        if (key != 0ull) k[atomicAdd(&cnt, 1)] = key;
    }
    __syncthreads();
    const int T = cnt;
    if (chunk == 0 && tid == 0) sortT[c] = T;

    for (int t = tid; t < T; t += BS) {
        unsigned long long key = k[t];
        int pos = 0;
        for (int u = 0; u < T; ++u) pos += (k[u] > key) ? 1 : 0;
        sk[pos] = key;
    }
    __syncthreads();

    const int start = chunk * CHSZ;
    const int end   = min(start + CHSZ, P);
    const float* pr = pred + (size_t)c * P * 7;
    for (int i = start + tid; i < end; i += BS) {
        unsigned long long kq =
            ((unsigned long long)__float_as_uint(pr[(size_t)i * 7 + 2]) << 32)
            | (unsigned)(P - 1 - i);
        int lo = 0;   // count of sorted-desc keys > kq (pads are 0, never > kq)
        #pragma unroll
        for (int step = 512; step > 0; step >>= 1)
            if (sk[lo + step - 1] > kq) lo += step;
        atomicAdd(&h[lo], 1);
    }
    __syncthreads();
    for (int j = tid; j < 1024; j += BS)
        if (h[j]) atomicAdd(&gHist[c * 1024 + j], h[j]);   // no-return
}

// ---------------- ap + mean: prefix over hist + closed-form + last-block ----
// (verbatim round 10 — passed.)
__global__ __launch_bounds__(BS) void ap2m_kernel(
        const int* __restrict__ sortT, const int* __restrict__ gHist,
        float* __restrict__ ap, unsigned int* __restrict__ doneCnt,
        float* __restrict__ out) {
    __shared__ int ha[1024];
    __shared__ int hb[1024];
    __shared__ float red[BS];
    const int c = blockIdx.x, tid = threadIdx.x;
    const int T = sortT[c];
    for (int j = tid; j < 1024; j += BS) ha[j] = gHist[c * 1024 + j];
    __syncthreads();
    int* src = ha; int* dst = hb;
    for (int o = 1; o < 1024; o <<= 1) {
        for (int j = tid; j < 1024; j += BS)
            dst[j] = src[j] + ((j >= o) ? src[j - o] : 0);
        __syncthreads();
        int* tmp = src; src = dst; dst = tmp;
    }
    float sum = 0.0f;
    for (int s = tid; s < T; s += BS) {
        int r = src[s] - 1;          // inclusive prefix minus self
        if (r >= 1) {
            float kf  = (float)(s + 1);
            float km  = (float)s;
            float ri  = __fdiv_rn(kf, 800.0f);
            float rim = __fdiv_rn(km, 800.0f);
            float pi  = __fdiv_rn(kf, (float)(r + 1));
            float pim = __fdiv_rn(km, (float)r);
            sum = __fadd_rn(sum,
                  __fmul_rn(__fmul_rn(__fsub_rn(ri, rim), __fadd_rn(pi, pim)), 0.5f));
        }
    }
    red[tid] = sum;
    __syncthreads();
    for (int s2 = BS / 2; s2 > 0; s2 >>= 1) {
        if (tid < s2) red[tid] = __fadd_rn(red[tid], red[tid + s2]);
        __syncthreads();
    }
    if (tid == 0) {
        ap[c] = red[0];
        __threadfence();                         // publish ap[c] device-wide
        unsigned int t = atomicAdd(doneCnt, 1u); // ticket
        if (t == C - 1) {                        // last block finishes the mean
            __threadfence();                     // acquire all ap[] writes
            float s = 0.0f;
            for (int c2 = 0; c2 < C; ++c2) s = __fadd_rn(s, ap[c2]);
            out[0] = __fdiv_rn(s, 80.0f);
        }
    }
}

extern "C" void kernel_launch(void* const* d_in, const int* in_sizes, int n_in,
                              void* d_out, int out_size, void* d_ws, size_t ws_size,
                              hipStream_t stream) {
    const float* pred = (const float*)d_in[0];   // [C, P, 7] f32
    const float* gt   = (const float*)d_in[1];   // [C, G, 7] f32
    float* out = (float*)d_out;

    // Workspace layout — 9,694,464 B total (verbatim round 10). Re-poisoned
    // 0xAA each call — gt_bin (folded inits) / pprep (cellB) / pscatter
    // (pIdxS) rewrite everything read-before-write.
    char* ws = (char*)d_ws;
    int*                sortT      = (int*)               (ws + 0);         //     320 B
    float*              ap         = (float*)             (ws + 512);       //     320 B
    unsigned int*       doneCnt    = (unsigned int*)      (ws + 896);       //       4 B
    int*                predCnt    = (int*)               (ws + 1024);      //  81920 B
    int*                predCur    = (int*)               (ws + 82944);     //  81920 B
    unsigned short*     gtCnt      = (unsigned short*)    (ws + 164864);    //  40960 B
    unsigned short*     gtOff      = (unsigned short*)    (ws + 205824);    //  40960 B
    unsigned short*     gtIdx      = (unsigned short*)    (ws + 246784);    // 128000 B
    float*              gtAbe      = (float*)             (ws + 374784);    // 256000 B
    float4*             gtBox      = (float4*)            (ws + 630784);    // 1.024 MB (16-aligned)
    unsigned long long* gtKey      = (unsigned long long*)(ws + 1654784);   // 512000 B
    int*                gHist      = (int*)               (ws + 2166784);   // 327680 B
    unsigned char*      cellB      = (unsigned char*)     (ws + 2494464);   // 2.4 MB
    unsigned short*     pIdxS      = (unsigned short*)    (ws + 4894464);   // 4.8 MB
    // end: 9694464 B

    const int P_BLK = (P + BS - 1) / BS;       // 118

    gt_bin_kernel<<<C, BS, 0, stream>>>(gt, gtCnt, gtOff, gtBox, gtAbe, gtIdx,
                                        gtKey, gHist, predCnt, predCur, doneCnt);
    pprep_kernel<<<dim3(P_BLK, C), BS, 0, stream>>>(pred, predCnt, cellB);
    pscatter_kernel<<<dim3(P_BLK, C), BS, 0, stream>>>(cellB, predCnt, predCur, pIdxS);
    match11_kernel<<<MPART * C, BS, 0, stream>>>(pred, pIdxS, gtOff, gtCnt,
                                                 gtBox, gtAbe, gtIdx, gtKey);
    histf_kernel<<<dim3(HCH, C), BS, 0, stream>>>(pred, gtKey, gHist, sortT);
    ap2m_kernel<<<C, BS, 0, stream>>>(sortT, gHist, ap, doneCnt, out);
}

// Round 12
// 246.110 us; speedup vs baseline: 1.1825x; 1.1825x over previous
//
#include <hip/hip_runtime.h>

// Problem constants (match reference)
#define C 80
#define P 30000
#define G 800
#define BS 256
#define NB 16           // 64-px cells over [0,1024); boxes binned by CENTER
#define NC (NB * NB)    // 256 cells per class
#define PPTM 4          // sorted slots per thread in match
#define TPBM (BS * PPTM)// 1024 sorted slots per match block
#define MPART ((P + TPBM - 1) / TPBM)   // 30 parts per class
#define HCH 8           // hist chunks per class (finale parallelism)
#define CHSZ ((P + HCH - 1) / HCH)   // 3750

// Center-binning prune (validated absmax 0.0 across rounds 1-5,7-11): IoU>0.5
// forces each box to contain the other's center in both dims, so any viable
// GT's center lies strictly inside the pred box -> candidate cells are
// exactly the cells the pred box overlaps. Pruned pairs provably have
// IoU <= 0.5; validity re-verified with the bit-exact reference division.
//
// Round-12 synthesis of rounds 10+11:
//  - XCD swizzle CONFIRMED (round 11: FETCH 172->39MB): keep. Consecutive
//    ids on one XCD walk parts of ONE class -> one 840KB slab L2-resident.
//  - ILP batching REFUTED (VGPR 20->100, occupancy 31->17%, match 82->119):
//    revert to round-10's serial per-rep body (VGPR ~20).
//  - Occupancy was GRID-limited in round 10 (1200 blocks = 4.7/CU): halve
//    TPBM -> 2400 blocks ~ 9.4/CU, LDS-capped 8/CU. L2-hot gathers (~200cy)
//    + ~8 waves/SIMD of TLP = latency finally hidden.
//
// Round-7 lesson kept everywhere: atomically-accumulated buffers (predCnt,
// gHist) cross a KERNEL BOUNDARY before being plain-read (XCD coherence).

// rank order = score desc, then pred-index asc. Packed key is monotone in
// that order (scores >= 0 so float bits are order-preserving). key==0 means
// "no match" (needs score==0.0f AND p==P-1 — probability ~0).
__device__ __forceinline__ unsigned long long pack_key(float s, int p) {
    return ((unsigned long long)__float_as_uint(s) << 32) | (unsigned)(P - 1 - p);
}

__device__ __forceinline__ int cell_coord(float v) {
    return min(max((int)(v * (1.0f / 64.0f)), 0), NB - 1);
}

__device__ __forceinline__ int cell_of_center(float cxf, float cyf) {
    return cell_coord(cyf) * NB + cell_coord(cxf);
}

// ---------------- gt binning: one block per class (count+scan+scatter) ------
// (verbatim round 10 — passed.) BS == NC == 256: thread t owns cell t.
// Zeroes this class's gtKey, gHist, predCnt, predCur, ticket.
__global__ __launch_bounds__(BS) void gt_bin_kernel(
        const float* __restrict__ gt,
        unsigned short* __restrict__ gtCnt, unsigned short* __restrict__ gtOff,
        float4* __restrict__ gtBox, float* __restrict__ gtAbe,
        unsigned short* __restrict__ gtIdx,
        unsigned long long* __restrict__ gtKey, int* __restrict__ gHist,
        int* __restrict__ predCnt, int* __restrict__ predCur,
        unsigned int* __restrict__ doneCnt) {
    __shared__ int h[NC], cur[NC];
    __shared__ int gcell[G];
    const int c = blockIdx.x, tid = threadIdx.x;
    h[tid] = 0;
    predCnt[c * NC + tid] = 0;                                       // folded init
    predCur[c * NC + tid] = 0;                                       // folded init
    if (c == 0 && tid == 0) *doneCnt = 0u;                           // folded init
    for (int i = tid; i < G; i += BS) gtKey[c * G + i] = 0ull;       // folded init
    for (int j = tid; j < 1024; j += BS) gHist[c * 1024 + j] = 0;    // folded init
    __syncthreads();
    for (int i = tid; i < G; i += BS) {
        const float* r = gt + ((size_t)c * G + i) * 7;
        int cl = cell_of_center(0.5f * (r[3] + r[5]), 0.5f * (r[4] + r[6]));
        gcell[i] = cl;
        atomicAdd(&h[cl], 1);
    }
    __syncthreads();
    const int v = h[tid];
    cur[tid] = v;
    __syncthreads();
    for (int o = 1; o < NC; o <<= 1) {   // inclusive scan, 8 steps
        int t = (tid >= o) ? cur[tid - o] : 0;
        __syncthreads();
        cur[tid] += t;
        __syncthreads();
    }
    const int excl = cur[tid] - v;
    gtOff[c * NC + tid] = (unsigned short)excl;
    gtCnt[c * NC + tid] = (unsigned short)v;
    __syncthreads();
    cur[tid] = excl;
    __syncthreads();
    for (int i = tid; i < G; i += BS) {
        const float* r = gt + ((size_t)c * G + i) * 7;   // L1-hot (2nd pass)
        float x1 = r[3], y1 = r[4], x2 = r[5], y2 = r[6];
        int slot = atomicAdd(&cur[gcell[i]], 1);
        gtBox[c * G + slot] = make_float4(x1, y1, x2, y2);
        // area + eps pre-folded: cross-compare uses sb = A + (area_g + eps);
        // the -inter terms of the two denominators cancel algebraically.
        gtAbe[c * G + slot] = __fadd_rn(__fmul_rn(__fsub_rn(x2, x1), __fsub_rn(y2, y1)), 1e-9f);
        gtIdx[c * G + slot] = (unsigned short)i;
    }
}

// ---------------- pprep: per-(class,cell) counts + cell cache ----------
// (verbatim round 10 — passed.)
__global__ __launch_bounds__(BS) void pprep_kernel(
        const float* __restrict__ pred, int* __restrict__ predCnt,
        unsigned char* __restrict__ cellB) {
    __shared__ int h[NC];
    const int c = blockIdx.y, tid = threadIdx.x;
    h[tid] = 0;
    __syncthreads();
    int p = blockIdx.x * BS + tid;
    if (p < P) {
        const float* r = pred + ((size_t)c * P + p) * 7;
        int cl = cell_of_center(0.5f * (r[3] + r[5]), 0.5f * (r[4] + r[6]));
        cellB[(size_t)c * P + p] = (unsigned char)cl;   // NC==256 fits uchar
        atomicAdd(&h[cl], 1);
    }
    __syncthreads();
    if (h[tid]) atomicAdd(&predCnt[c * NC + tid], h[tid]);   // no-return
}

// ---------------- pscatter: cell-sorted ushort index scatter ----------
// (verbatim round 10 — passed.)
__global__ __launch_bounds__(BS) void pscatter_kernel(
        const unsigned char* __restrict__ cellB, const int* __restrict__ predCnt,
        int* __restrict__ predCur, unsigned short* __restrict__ pIdxS) {
    __shared__ int h[NC], base[NC], sc[NC];
    const int c = blockIdx.y, tid = threadIdx.x;
    h[tid] = 0;
    sc[tid] = predCnt[c * NC + tid];
    const int v = sc[tid];
    __syncthreads();
    int p = blockIdx.x * BS + tid;
    int cellv = 0, lr = 0;
    if (p < P) {
        cellv = cellB[(size_t)c * P + p];
        lr = atomicAdd(&h[cellv], 1);   // LDS, local rank
    }
    __syncthreads();
    for (int o = 1; o < NC; o <<= 1) {  // inclusive scan (proven pattern)
        int t = (tid >= o) ? sc[tid - o] : 0;
        __syncthreads();
        sc[tid] += t;
        __syncthreads();
    }
    if (h[tid]) base[tid] = (sc[tid] - v) + atomicAdd(&predCur[c * NC + tid], h[tid]);
    __syncthreads();
    if (p < P) pIdxS[(size_t)c * P + base[cellv] + lr] = (unsigned short)p;
}

// ---------------- match: wave-coherent slots + XCD swizzle, serial body ----
// 1D grid of 2400: id = (c%8) + 8*(part + 30*(c/8)) -> all 30 parts of a
// class share id%8 (one XCD under the %NXCD dispatch heuristic) and are
// consecutive in id -> one class slab L2-resident at a time. Serial round-10
// rep body (VGPR ~20) + 2400 blocks (~9.4/CU, LDS-capped 8/CU) = TLP hides
// the L2-hot gather latency. Pair arithmetic, GT order, epilogue
// bit-identical to proven rounds 2-11.
__global__ __launch_bounds__(BS) void match12_kernel(
        const float* __restrict__ pred, const unsigned short* __restrict__ pIdxS,
        const unsigned short* __restrict__ gtOff, const unsigned short* __restrict__ gtCnt,
        const float4* __restrict__ gtBox, const float* __restrict__ gtAbe,
        const unsigned short* __restrict__ gtIdx,
        unsigned long long* __restrict__ gtKey) {
    __shared__ float4 sB[G];                        // 12.8 KB
    __shared__ float  sE[G];                        //  3.2 KB
    __shared__ unsigned short sG[G];                //  1.6 KB
    __shared__ unsigned short sOff[NC], sCnt[NC];   //  1.0 KB => 18.6 KB
    const int id  = blockIdx.x;
    const int xcd = id & 7;
    const int q   = id >> 3;
    const int part = q % MPART;
    const int c    = xcd + 8 * (q / MPART);
    const int tid = threadIdx.x;
    const int s0 = part * TPBM;

    for (int i = tid; i < G; i += BS) {
        sB[i] = gtBox[c * G + i];
        sE[i] = gtAbe[c * G + i];
        sG[i] = gtIdx[c * G + i];
    }
    sOff[tid] = gtOff[c * NC + tid];   // BS == NC
    sCnt[tid] = gtCnt[c * NC + tid];
    __syncthreads();

    const size_t cp = (size_t)c * P;
    #pragma unroll 1
    for (int rep = 0; rep < PPTM; ++rep) {
        const int slot = s0 + rep * BS + tid;
        if (slot < P) {
            const int p = pIdxS[cp + slot];           // coalesced ushort
            const float* r = pred + (cp + p) * 7;     // L2-hot gather (swizzle)
            float ax1 = r[3], ay1 = r[4], ax2 = r[5], ay2 = r[6];
            float A = __fmul_rn(__fsub_rn(ax2, ax1), __fsub_rn(ay2, ay1));
            // candidate cells: those the pred box overlaps (any GT center
            // with iou>0.5 lies strictly inside the pred box)
            const int x0 = cell_coord(ax1), x1 = cell_coord(ax2);
            const int y0 = cell_coord(ay1), y1 = cell_coord(ay2);
            float IN = 0.0f, SB = 1.0f;
            int mj = -1;
            for (int yy = y0; yy <= y1; ++yy) {
                const int rowb = yy * NB;
                const int jb = sOff[rowb + x0];
                const int je = sOff[rowb + x1] + sCnt[rowb + x1];
                #pragma unroll 2
                for (int j = jb; j < je; ++j) {
                    float4 b = sB[j];
                    float lx = fmaxf(ax1, b.x), ly = fmaxf(ay1, b.y);
                    float rx = fminf(ax2, b.z), ry = fminf(ay2, b.w);
                    float wx = fmaxf(__fsub_rn(rx, lx), 0.0f);
                    float wy = fmaxf(__fsub_rn(ry, ly), 0.0f);
                    float in = __fmul_rn(wx, wy);
                    float sb = __fadd_rn(A, sE[j]);
                    bool  up = __fmul_rn(in, SB) > __fmul_rn(IN, sb);
                    IN = up ? in : IN; SB = up ? sb : SB; mj = up ? j : mj;
                }
            }
            if (IN > 0.0f) {   // zero-inter preds can never be valid
                float4 b = sB[mj];
                float area = __fmul_rn(__fsub_rn(b.z, b.x), __fsub_rn(b.w, b.y));
                float dn = __fadd_rn(__fsub_rn(__fadd_rn(A, area), IN), 1e-9f);
                float iou = __fdiv_rn(IN, dn);   // exact reference value
                if (iou > 0.5f) {
                    float sscore = r[2];         // rare path, L1-hot line
                    atomicMax(&gtKey[c * G + sG[mj]], pack_key(sscore, p));
                }
            }
        }
    }
}

// ---------------- histf: compact+sort (x8 redundant) + chunked hist ------
// (verbatim round 10 — passed.) gHist consumed only in the NEXT launch.
__global__ __launch_bounds__(BS) void histf_kernel(
        const float* __restrict__ pred,
        const unsigned long long* __restrict__ gtKey,
        int* __restrict__ gHist, int* __restrict__ sortT) {
    __shared__ unsigned long long k[G];     // 6.4 KB compacted keys
    __shared__ unsigned long long sk[1024]; // 8 KB sorted-desc keys (pad=0)
    __shared__ int h[1024];                 // 4 KB local hist
    __shared__ int cnt;
    const int c = blockIdx.y, chunk = blockIdx.x, tid = threadIdx.x;

    if (tid == 0) cnt = 0;
    for (int j = tid; j < 1024; j += BS) { sk[j] = 0ull; h[j] = 0; }
    __syncthreads();
    for (int i = tid; i < G; i += BS) {
        unsigned long long key = gtKey[c * G + i];
        if (key != 0ull) k[atomicAdd(&cnt, 1)] = key;
    }
    __syncthreads();
    const int T = cnt;
    if (chunk == 0 && tid == 0) sortT[c] = T;

    for (int t = tid; t < T; t += BS) {
        unsigned long long key = k[t];
        int pos = 0;
        for (int u = 0; u < T; ++u) pos += (k[u] > key) ? 1 : 0;
        sk[pos] = key;
    }
    __syncthreads();

    const int start = chunk * CHSZ;
    const int end   = min(start + CHSZ, P);
    const float* pr = pred + (size_t)c * P * 7;
    for (int i = start + tid; i < end; i += BS) {
        unsigned long long kq =
            ((unsigned long long)__float_as_uint(pr[(size_t)i * 7 + 2]) << 32)
            | (unsigned)(P - 1 - i);
        int lo = 0;   // count of sorted-desc keys > kq (pads are 0, never > kq)
        #pragma unroll
        for (int step = 512; step > 0; step >>= 1)
            if (sk[lo + step - 1] > kq) lo += step;
        atomicAdd(&h[lo], 1);
    }
    __syncthreads();
    for (int j = tid; j < 1024; j += BS)
        if (h[j]) atomicAdd(&gHist[c * 1024 + j], h[j]);   // no-return
}

// ---------------- ap + mean: prefix over hist + closed-form + last-block ----
// (verbatim round 10 — passed.)
__global__ __launch_bounds__(BS) void ap2m_kernel(
        const int* __restrict__ sortT, const int* __restrict__ gHist,
        float* __restrict__ ap, unsigned int* __restrict__ doneCnt,
        float* __restrict__ out) {
    __shared__ int ha[1024];
    __shared__ int hb[1024];
    __shared__ float red[BS];
    const int c = blockIdx.x, tid = threadIdx.x;
    const int T = sortT[c];
    for (int j = tid; j < 1024; j += BS) ha[j] = gHist[c * 1024 + j];
    __syncthreads();
    int* src = ha; int* dst = hb;
    for (int o = 1; o < 1024; o <<= 1) {
        for (int j = tid; j < 1024; j += BS)
            dst[j] = src[j] + ((j >= o) ? src[j - o] : 0);
        __syncthreads();
        int* tmp = src; src = dst; dst = tmp;
    }
    float sum = 0.0f;
    for (int s = tid; s < T; s += BS) {
        int r = src[s] - 1;          // inclusive prefix minus self
        if (r >= 1) {
            float kf  = (float)(s + 1);
            float km  = (float)s;
            float ri  = __fdiv_rn(kf, 800.0f);
            float rim = __fdiv_rn(km, 800.0f);
            float pi  = __fdiv_rn(kf, (float)(r + 1));
            float pim = __fdiv_rn(km, (float)r);
            sum = __fadd_rn(sum,
                  __fmul_rn(__fmul_rn(__fsub_rn(ri, rim), __fadd_rn(pi, pim)), 0.5f));
        }
    }
    red[tid] = sum;
    __syncthreads();
    for (int s2 = BS / 2; s2 > 0; s2 >>= 1) {
        if (tid < s2) red[tid] = __fadd_rn(red[tid], red[tid + s2]);
        __syncthreads();
    }
    if (tid == 0) {
        ap[c] = red[0];
        __threadfence();                         // publish ap[c] device-wide
        unsigned int t = atomicAdd(doneCnt, 1u); // ticket
        if (t == C - 1) {                        // last block finishes the mean
            __threadfence();                     // acquire all ap[] writes
            float s = 0.0f;
            for (int c2 = 0; c2 < C; ++c2) s = __fadd_rn(s, ap[c2]);
            out[0] = __fdiv_rn(s, 80.0f);
        }
    }
}

extern "C" void kernel_launch(void* const* d_in, const int* in_sizes, int n_in,
                              void* d_out, int out_size, void* d_ws, size_t ws_size,
                              hipStream_t stream) {
    const float* pred = (const float*)d_in[0];   // [C, P, 7] f32
    const float* gt   = (const float*)d_in[1];   // [C, G, 7] f32
    float* out = (float*)d_out;

    // Workspace layout — 9,694,464 B total (verbatim round 10). Re-poisoned
    // 0xAA each call — gt_bin (folded inits) / pprep (cellB) / pscatter
    // (pIdxS) rewrite everything read-before-write.
    char* ws = (char*)d_ws;
    int*                sortT      = (int*)               (ws + 0);         //     320 B
    float*              ap         = (float*)             (ws + 512);       //     320 B
    unsigned int*       doneCnt    = (unsigned int*)      (ws + 896);       //       4 B
    int*                predCnt    = (int*)               (ws + 1024);      //  81920 B
    int*                predCur    = (int*)               (ws + 82944);     //  81920 B
    unsigned short*     gtCnt      = (unsigned short*)    (ws + 164864);    //  40960 B
    unsigned short*     gtOff      = (unsigned short*)    (ws + 205824);    //  40960 B
    unsigned short*     gtIdx      = (unsigned short*)    (ws + 246784);    // 128000 B
    float*              gtAbe      = (float*)             (ws + 374784);    // 256000 B
    float4*             gtBox      = (float4*)            (ws + 630784);    // 1.024 MB (16-aligned)
    unsigned long long* gtKey      = (unsigned long long*)(ws + 1654784);   // 512000 B
    int*                gHist      = (int*)               (ws + 2166784);   // 327680 B
    unsigned char*      cellB      = (unsigned char*)     (ws + 2494464);   // 2.4 MB
    unsigned short*     pIdxS      = (unsigned short*)    (ws + 4894464);   // 4.8 MB
    // end: 9694464 B

    const int P_BLK = (P + BS - 1) / BS;       // 118

    gt_bin_kernel<<<C, BS, 0, stream>>>(gt, gtCnt, gtOff, gtBox, gtAbe, gtIdx,
                                        gtKey, gHist, predCnt, predCur, doneCnt);
    pprep_kernel<<<dim3(P_BLK, C), BS, 0, stream>>>(pred, predCnt, cellB);
    pscatter_kernel<<<dim3(P_BLK, C), BS, 0, stream>>>(cellB, predCnt, predCur, pIdxS);
    match12_kernel<<<MPART * C, BS, 0, stream>>>(pred, pIdxS, gtOff, gtCnt,
                                                 gtBox, gtAbe, gtIdx, gtKey);
    histf_kernel<<<dim3(HCH, C), BS, 0, stream>>>(pred, gtKey, gHist, sortT);
    ap2m_kernel<<<C, BS, 0, stream>>>(sortT, gHist, ap, doneCnt, out);
}